// Round 12
// baseline (175.040 us; speedup 1.0000x reference)
//
#include <hip/hip_runtime.h>
#include <hip/hip_bf16.h>

#define HID   128
#define NPB   64      // nodes per node-kernel block
#define PITCH 136     // h0 LDS row pitch (bf16 elems): 128 + 8 pad
#define CH0   32768   // edge-binning chunk-0 size (128 KB LDS); assumes N<=65536
#define FRAGN 16384   // shorts per repacked W1: 8 j16 x 4 s x 64 lanes x 8 bf16
#define NPREP 20      // prep blocks fused into node_g (20*256 = 5120 prep ids)
#define DONE  0x13572468

typedef float f32x4  __attribute__((ext_vector_type(4)));
typedef short bf16x8 __attribute__((ext_vector_type(8)));

__device__ __forceinline__ float fast_tanh(float x) {
    // tanh(x) = 1 - 2/(e^{2x}+1); v_rcp_f32 instead of IEEE div
    const float e = __expf(2.0f * x);
    return fmaf(-2.0f, __builtin_amdgcn_rcpf(e + 1.0f), 1.0f);
}

__device__ __forceinline__ short f2bf(float x) {
    union { __hip_bfloat16 h; short s; } u;
    u.h = __float2bfloat16(x);
    return u.s;
}

// ---------------------------------------------------------------------------
// node g_phi (+fused prep): gsq[n] = (MLP3(v,a))^2.
// Blocks 0..NPREP-1 first repack W1/b/w2 into lane-fragment order (both g and
// f matrices), publish via device-scope flags; all blocks acquire-wait before
// loading fragments. Safe: __launch_bounds__(256,4) => >=4 blocks/CU => >=1024
// co-resident slots >= 782 blocks, so spinners cannot starve prep blocks.
// ---------------------------------------------------------------------------
__global__ __launch_bounds__(256, 4) void node_g_kernel(
    const float* __restrict__ v, const float* __restrict__ a,
    const float* __restrict__ g0_w, const float* __restrict__ g0_b,
    const float* __restrict__ g1_w, const float* __restrict__ g1_b,
    const float* __restrict__ g2_w,
    const float* __restrict__ f1_w, const float* __restrict__ f1_b,
    const float* __restrict__ f2_w,
    short* __restrict__ gfrag, short* __restrict__ ffrag,
    float* __restrict__ gbw, float* __restrict__ fbw,
    int* __restrict__ flags,
    const float* __restrict__ g2_b,
    float* __restrict__ gsq, int N)
{
    const int t    = threadIdx.x;
    const int lane = t & 63;
    const int wq   = t >> 6;
    const int base = blockIdx.x * NPB;
    const int m    = lane & 15;
    const int kg   = lane >> 4;

    __shared__ __align__(16) __hip_bfloat16 h0bf[NPB * PITCH];
    __shared__ float xv[NPB];
    __shared__ float xa[2 * NPB];
    __shared__ float red[4][4][16];

    // ---- fused prep (blocks 0..NPREP-1) ----
    if (blockIdx.x < NPREP) {
        const int id  = blockIdx.x * 256 + t;    // 0..5119
        const int mat = (id >= 2560);
        const int r   = id - (mat ? 2560 : 0);
        const float* __restrict__ w1 = mat ? f1_w : g1_w;
        const float* __restrict__ b1 = mat ? f1_b : g1_b;
        const float* __restrict__ w2 = mat ? f2_w : g2_w;
        short* __restrict__ frag = mat ? ffrag : gfrag;
        float* __restrict__ bw   = mat ? fbw   : gbw;

        if (r < 2048) {
            const int j16 = r >> 8;
            const int s   = (r >> 6) & 3;
            const int ln  = r & 63;
            const int mm = ln & 15, kk = ln >> 4;
            const int j  = j16 * 16 + mm;
            const int k0 = 32 * s + 8 * kk;
            bf16x8 f;
#pragma unroll
            for (int e = 0; e < 8; ++e) f[e] = f2bf(w1[(k0 + e) * HID + j]);
            *(bf16x8*)&frag[r * 8] = f;
        } else if (r < 2560) {
            const int q = r - 2048;
            const int j16 = q >> 6, ln = q & 63, kk = ln >> 4;
#pragma unroll
            for (int rr = 0; rr < 4; ++rr) {
                bw[q * 8 + rr]     = b1[j16 * 16 + 4 * kk + rr];
                bw[q * 8 + 4 + rr] = w2[j16 * 16 + 4 * kk + rr];
            }
        }
        __threadfence();
        __syncthreads();
        if (t == 0)
            __hip_atomic_store(&flags[blockIdx.x], DONE,
                               __ATOMIC_RELEASE, __HIP_MEMORY_SCOPE_AGENT);
    }

    // ---- stage node inputs (independent of prep; overlaps the wait) ----
    if (t < NPB) {
        int node = base + t; if (node >= N) node = N - 1;
        xv[t] = v[node];
    } else if (t >= 128) {
        int idx = 2 * base + (t - 128);
        const int lim = 2 * N - 1; if (idx > lim) idx = lim;
        xa[t - 128] = a[idx];
    }

    // ---- wait for all prep flags ----
    if (t < NPREP) {
        while (__hip_atomic_load(&flags[t], __ATOMIC_ACQUIRE,
                                 __HIP_MEMORY_SCOPE_AGENT) != DONE) {
            __builtin_amdgcn_s_sleep(8);
        }
    }
    __syncthreads();

    // ---- persistent W1 fragments: one coalesced 16B load each ----
    bf16x8 afrag[2][4];
    float b1v[2][4], w2v[2][4];
    const bf16x8* __restrict__ fb = (const bf16x8*)gfrag;
#pragma unroll
    for (int jt = 0; jt < 2; ++jt) {
        const int j16 = 2 * wq + jt;
#pragma unroll
        for (int s = 0; s < 4; ++s)
            afrag[jt][s] = fb[(j16 * 4 + s) * 64 + lane];
        const f32x4 bv = *(const f32x4*)&gbw[(j16 * 64 + lane) * 8];
        const f32x4 wv = *(const f32x4*)&gbw[(j16 * 64 + lane) * 8 + 4];
#pragma unroll
        for (int r = 0; r < 4; ++r) { b1v[jt][r] = bv[r]; w2v[jt][r] = wv[r]; }
    }

    {   // layer 0
        const int j    = t & 127;
        const int half = t >> 7;
        const float w00 = g0_w[0 * HID + j];
        const float w01 = g0_w[1 * HID + j];
        const float w02 = g0_w[2 * HID + j];
        const float b0  = g0_b[j];
#pragma unroll 4
        for (int i = 0; i < 32; ++i) {
            const int nn = half * 32 + i;
            h0bf[nn * PITCH + j] = __float2bfloat16(
                fast_tanh(b0 + xv[nn] * w00 + xa[2 * nn] * w01 + xa[2 * nn + 1] * w02));
        }
    }
    __syncthreads();

#pragma unroll
    for (int nt = 0; nt < 4; ++nt) {
        const int n = nt * 16 + m;
        f32x4 acc0 = {0.f, 0.f, 0.f, 0.f};
        f32x4 acc1 = {0.f, 0.f, 0.f, 0.f};
#pragma unroll
        for (int s = 0; s < 4; ++s) {
            const bf16x8 b = *(const bf16x8*)&h0bf[n * PITCH + 32 * s + 8 * kg];
            acc0 = __builtin_amdgcn_mfma_f32_16x16x32_bf16(afrag[0][s], b, acc0, 0, 0, 0);
            acc1 = __builtin_amdgcn_mfma_f32_16x16x32_bf16(afrag[1][s], b, acc1, 0, 0, 0);
        }
        float p = 0.f;
#pragma unroll
        for (int r = 0; r < 4; ++r) {
            p += w2v[0][r] * fast_tanh(acc0[r] + b1v[0][r]);
            p += w2v[1][r] * fast_tanh(acc1[r] + b1v[1][r]);
        }
        p += __shfl_down(p, 32);
        p += __shfl_down(p, 16);
        if (lane < 16) red[wq][nt][lane] = p;
    }
    __syncthreads();

    if (t < NPB) {
        const int node = base + t;
        if (node < N) {
            const float g = red[0][t >> 4][t & 15] + red[1][t >> 4][t & 15]
                          + red[2][t >> 4][t & 15] + red[3][t >> 4][t & 15]
                          + g2_b[0];
            gsq[node] = g * g;
        }
    }
}

// ---------------------------------------------------------------------------
// edge scatter via LDS binning: 2 chunks x B parts; no global atomics.
// ---------------------------------------------------------------------------
__global__ __launch_bounds__(1024) void edge_kernel(
    const int* __restrict__ src, const int* __restrict__ dst,
    const float* __restrict__ W, const float* __restrict__ gsq,
    __hip_bfloat16* __restrict__ partial, int B, int N, int Np, int E)
{
    __shared__ float loc[CH0];
    const int t = threadIdx.x;
    const int c = blockIdx.x >> 7;          // requires 2B == 256 blocks
    const int p = blockIdx.x & 127;

    int chN = c ? (N - CH0) : CH0;
    if (chN > CH0) chN = CH0; if (chN < 0) chN = 0;

    const f32x4 z4 = {0.f, 0.f, 0.f, 0.f};
    const int chZ = (chN + 3) & ~3;
    for (int i = 4 * t; i < chZ; i += 4096) *(f32x4*)&loc[i] = z4;
    __syncthreads();

    int cnt = (E + B - 1) / B;
    cnt = (cnt + 3) & ~3;
    const int start = p * cnt;
    int end = start + cnt; if (end > E) end = E;
    const int coff = c << 15;

    if (start < end) {
        const int nvec = (end - start) & ~3;
        for (int i = 4 * t; i < nvec; i += 4096) {
            const int e = start + i;
            const int4   s4 = *(const int4*)&src[e];
            const int4   d4 = *(const int4*)&dst[e];
            const float4 w4 = *(const float4*)&W[e];
            if ((d4.x >> 15) == c) atomicAdd(&loc[d4.x - coff], w4.x * gsq[s4.x]);
            if ((d4.y >> 15) == c) atomicAdd(&loc[d4.y - coff], w4.y * gsq[s4.y]);
            if ((d4.z >> 15) == c) atomicAdd(&loc[d4.z - coff], w4.z * gsq[s4.z]);
            if ((d4.w >> 15) == c) atomicAdd(&loc[d4.w - coff], w4.w * gsq[s4.w]);
        }
        for (int e = start + nvec + t; e < end; e += 1024) {
            const int d = dst[e];
            if ((d >> 15) == c) atomicAdd(&loc[d - coff], W[e] * gsq[src[e]]);
        }
    }
    __syncthreads();

    __hip_bfloat16* __restrict__ dp = partial + (size_t)p * Np + coff;
    const int chV = chN & ~7;
    for (int i = 8 * t; i < chV; i += 8192) {
        const f32x4 lo = *(const f32x4*)&loc[i];
        const f32x4 hi = *(const f32x4*)&loc[i + 4];
        bf16x8 o;
#pragma unroll
        for (int r = 0; r < 4; ++r) { o[r] = f2bf(lo[r]); o[4 + r] = f2bf(hi[r]); }
        *(bf16x8*)&dp[i] = o;
    }
    for (int i = chV + t; i < chN; i += 1024) dp[i] = __float2bfloat16(loc[i]);
}

// ---------------------------------------------------------------------------
// node f_theta: out[n] = MLP3(v, a, msg, excitation); msg = sum of B partials
// (ffrag/fbw ready: produced inside node_g, two dispatches upstream)
// ---------------------------------------------------------------------------
__global__ __launch_bounds__(256) void node_f_kernel(
    const float* __restrict__ v, const float* __restrict__ a,
    const float* __restrict__ exc, const __hip_bfloat16* __restrict__ partial,
    int B, int Np,
    const float* __restrict__ f0_w, const float* __restrict__ f0_b,
    const short* __restrict__ ffrag, const float* __restrict__ fbw,
    const float* __restrict__ f2_b,
    float* __restrict__ out, int N)
{
    const int t    = threadIdx.x;
    const int lane = t & 63;
    const int wq   = t >> 6;
    const int base = blockIdx.x * NPB;
    const int m    = lane & 15;
    const int kg   = lane >> 4;

    __shared__ __align__(16) __hip_bfloat16 h0bf[NPB * PITCH];
    __shared__ float xv[NPB];
    __shared__ float xe[NPB];
    __shared__ float xa[2 * NPB];
    __shared__ float xm4[4][NPB];
    __shared__ float red[4][4][16];

    if (t < NPB) {
        int node = base + t; if (node >= N) node = N - 1;
        xv[t] = v[node];
    } else if (t < 128) {
        int node = base + (t - 64); if (node >= N) node = N - 1;
        xe[t - 64] = exc[node];
    } else {
        int idx = 2 * base + (t - 128);
        const int lim = 2 * N - 1; if (idx > lim) idx = lim;
        xa[t - 128] = a[idx];
    }
    {
        const int n16 = t & 63, grp = t >> 6;
        int node = base + n16; if (node >= N) node = N - 1;
        const int pb = B >> 2;
        float s = 0.f;
        for (int p = grp * pb; p < (grp + 1) * pb; ++p)
            s += __bfloat162float(partial[(size_t)p * Np + node]);
        xm4[grp][n16] = s;
    }

    bf16x8 afrag[2][4];
    float b1v[2][4], w2v[2][4];
    const bf16x8* __restrict__ fb = (const bf16x8*)ffrag;
#pragma unroll
    for (int jt = 0; jt < 2; ++jt) {
        const int j16 = 2 * wq + jt;
#pragma unroll
        for (int s = 0; s < 4; ++s)
            afrag[jt][s] = fb[(j16 * 4 + s) * 64 + lane];
        const f32x4 bv = *(const f32x4*)&fbw[(j16 * 64 + lane) * 8];
        const f32x4 wv = *(const f32x4*)&fbw[(j16 * 64 + lane) * 8 + 4];
#pragma unroll
        for (int r = 0; r < 4; ++r) { b1v[jt][r] = bv[r]; w2v[jt][r] = wv[r]; }
    }
    __syncthreads();

    {   // layer 0 (5 inputs)
        const int j    = t & 127;
        const int half = t >> 7;
        const float w00 = f0_w[0 * HID + j];
        const float w01 = f0_w[1 * HID + j];
        const float w02 = f0_w[2 * HID + j];
        const float w03 = f0_w[3 * HID + j];
        const float w04 = f0_w[4 * HID + j];
        const float b0  = f0_b[j];
#pragma unroll 4
        for (int i = 0; i < 32; ++i) {
            const int nn = half * 32 + i;
            const float x3 = (xm4[0][nn] + xm4[1][nn]) + (xm4[2][nn] + xm4[3][nn]);
            h0bf[nn * PITCH + j] = __float2bfloat16(
                fast_tanh(b0 + xv[nn] * w00 + xa[2 * nn] * w01 + xa[2 * nn + 1] * w02
                             + x3 * w03 + xe[nn] * w04));
        }
    }
    __syncthreads();

#pragma unroll
    for (int nt = 0; nt < 4; ++nt) {
        const int n = nt * 16 + m;
        f32x4 acc0 = {0.f, 0.f, 0.f, 0.f};
        f32x4 acc1 = {0.f, 0.f, 0.f, 0.f};
#pragma unroll
        for (int s = 0; s < 4; ++s) {
            const bf16x8 b = *(const bf16x8*)&h0bf[n * PITCH + 32 * s + 8 * kg];
            acc0 = __builtin_amdgcn_mfma_f32_16x16x32_bf16(afrag[0][s], b, acc0, 0, 0, 0);
            acc1 = __builtin_amdgcn_mfma_f32_16x16x32_bf16(afrag[1][s], b, acc1, 0, 0, 0);
        }
        float p = 0.f;
#pragma unroll
        for (int r = 0; r < 4; ++r) {
            p += w2v[0][r] * fast_tanh(acc0[r] + b1v[0][r]);
            p += w2v[1][r] * fast_tanh(acc1[r] + b1v[1][r]);
        }
        p += __shfl_down(p, 32);
        p += __shfl_down(p, 16);
        if (lane < 16) red[wq][nt][lane] = p;
    }
    __syncthreads();

    if (t < NPB) {
        const int node = base + t;
        if (node < N) {
            out[node] = red[0][t >> 4][t & 15] + red[1][t >> 4][t & 15]
                      + red[2][t >> 4][t & 15] + red[3][t >> 4][t & 15]
                      + f2_b[0];
        }
    }
}

extern "C" void kernel_launch(void* const* d_in, const int* in_sizes, int n_in,
                              void* d_out, int out_size, void* d_ws, size_t ws_size,
                              hipStream_t stream)
{
    const float* v    = (const float*)d_in[0];
    const float* exc  = (const float*)d_in[1];
    const int*   esrc = (const int*)d_in[2];
    const int*   edst = (const int*)d_in[3];
    const float* a    = (const float*)d_in[4];
    const float* W    = (const float*)d_in[5];
    const float* g0_w = (const float*)d_in[6];
    const float* g0_b = (const float*)d_in[7];
    const float* g1_w = (const float*)d_in[8];
    const float* g1_b = (const float*)d_in[9];
    const float* g2_w = (const float*)d_in[10];
    const float* g2_b = (const float*)d_in[11];
    const float* f0_w = (const float*)d_in[12];
    const float* f0_b = (const float*)d_in[13];
    const float* f1_w = (const float*)d_in[14];
    const float* f1_b = (const float*)d_in[15];
    const float* f2_w = (const float*)d_in[16];
    const float* f2_b = (const float*)d_in[17];

    const int N = in_sizes[0];   // 50000
    const int E = in_sizes[2];   // 1600000

    const int B  = 128;                       // edge parts (grid = 2*B = 256)
    const int Np = (N + 7) & ~7;              // bf16 partial pitch

    float* gsq = (float*)d_ws;                               // N floats
    __hip_bfloat16* partial = (__hip_bfloat16*)(gsq + N);    // B*Np bf16
    short* gfrag = (short*)(partial + (size_t)B * Np);       // FRAGN shorts
    short* ffrag = gfrag + FRAGN;                            // FRAGN shorts
    float* gbw   = (float*)(ffrag + FRAGN);                  // 4096 floats
    float* fbw   = gbw + 4096;                               // 4096 floats
    int*   flags = (int*)(fbw + 4096);                       // NPREP ints

    const int nblocks = (N + NPB - 1) / NPB;   // 782

    node_g_kernel<<<nblocks, 256, 0, stream>>>(v, a, g0_w, g0_b,
                                               g1_w, g1_b, g2_w,
                                               f1_w, f1_b, f2_w,
                                               gfrag, ffrag, gbw, fbw, flags,
                                               g2_b, gsq, N);

    edge_kernel<<<2 * B, 1024, 0, stream>>>(esrc, edst, W, gsq, partial,
                                            B, N, Np, E);

    node_f_kernel<<<nblocks, 256, 0, stream>>>(v, a, exc, partial, B, Np,
                                               f0_w, f0_b, ffrag, fbw, f2_b,
                                               (float*)d_out, N);
}

// Round 13
// 143.631 us; speedup vs baseline: 1.2187x; 1.2187x over previous
//
#include <hip/hip_runtime.h>
#include <hip/hip_bf16.h>

#define HID   128
#define NPB   64      // nodes per node-kernel block
#define PITCH 136     // h0 LDS row pitch (bf16 elems): 128 + 8 pad
#define CH0   32768   // edge-binning chunk-0 size (128 KB LDS); assumes N<=65536
#define FRAGN 16384   // shorts per repacked W1: 8 j16 x 4 s x 64 lanes x 8 bf16

typedef float f32x4  __attribute__((ext_vector_type(4)));
typedef short bf16x8 __attribute__((ext_vector_type(8)));

__device__ __forceinline__ float fast_tanh(float x) {
    // tanh(x) = 1 - 2/(e^{2x}+1); v_rcp_f32 instead of IEEE div
    const float e = __expf(2.0f * x);
    return fmaf(-2.0f, __builtin_amdgcn_rcpf(e + 1.0f), 1.0f);
}

__device__ __forceinline__ short f2bf(float x) {
    union { __hip_bfloat16 h; short s; } u;
    u.h = __float2bfloat16(x);
    return u.s;
}

// ---------------------------------------------------------------------------
// prep: repack W1 into lane-fragment order (bf16) + pack b1/w2 per lane.
// Kept as a separate 2.5 us dispatch: both in-kernel alternatives measured
// WORSE (cooperative grid.sync +109 us, device-scope flag spin +29 us).
// ---------------------------------------------------------------------------
__global__ __launch_bounds__(256) void prep_kernel(
    const float* __restrict__ g1_w, const float* __restrict__ g1_b, const float* __restrict__ g2_w,
    const float* __restrict__ f1_w, const float* __restrict__ f1_b, const float* __restrict__ f2_w,
    short* __restrict__ gfrag, short* __restrict__ ffrag,
    float* __restrict__ gbw, float* __restrict__ fbw)
{
    const int id  = blockIdx.x * 256 + threadIdx.x;   // 0..5119
    const int mat = (id >= 2560);
    const int r   = id - (mat ? 2560 : 0);
    const float* __restrict__ w1 = mat ? f1_w : g1_w;
    const float* __restrict__ b1 = mat ? f1_b : g1_b;
    const float* __restrict__ w2 = mat ? f2_w : g2_w;
    short* __restrict__ frag = mat ? ffrag : gfrag;
    float* __restrict__ bw   = mat ? fbw   : gbw;

    if (r < 2048) {
        const int j16  = r >> 8;
        const int s    = (r >> 6) & 3;
        const int lane = r & 63;
        const int m = lane & 15, kg = lane >> 4;
        const int j  = j16 * 16 + m;
        const int k0 = 32 * s + 8 * kg;
        bf16x8 f;
#pragma unroll
        for (int e = 0; e < 8; ++e) f[e] = f2bf(w1[(k0 + e) * HID + j]);
        *(bf16x8*)&frag[r * 8] = f;
    } else if (r < 2560) {
        const int q = r - 2048;            // 0..511
        const int j16 = q >> 6, lane = q & 63, kg = lane >> 4;
#pragma unroll
        for (int rr = 0; rr < 4; ++rr) {
            bw[q * 8 + rr]     = b1[j16 * 16 + 4 * kg + rr];
            bw[q * 8 + 4 + rr] = w2[j16 * 16 + 4 * kg + rr];
        }
    }
}

// ---------------------------------------------------------------------------
// node g_phi: gsq[n] = (MLP3(v,a))^2.  Layer-1 = MFMA bf16, layers 0/2 fp32.
// ---------------------------------------------------------------------------
__global__ __launch_bounds__(256) void node_g_kernel(
    const float* __restrict__ v, const float* __restrict__ a,
    const float* __restrict__ g0_w, const float* __restrict__ g0_b,
    const short* __restrict__ gfrag, const float* __restrict__ gbw,
    const float* __restrict__ g2_b,
    float* __restrict__ gsq, int N)
{
    const int t    = threadIdx.x;
    const int lane = t & 63;
    const int wq   = t >> 6;
    const int base = blockIdx.x * NPB;
    const int m    = lane & 15;
    const int kg   = lane >> 4;

    __shared__ __align__(16) __hip_bfloat16 h0bf[NPB * PITCH];
    __shared__ float xv[NPB];
    __shared__ float xa[2 * NPB];
    __shared__ float red[4][4][16];

    if (t < NPB) {
        int node = base + t; if (node >= N) node = N - 1;
        xv[t] = v[node];
    } else if (t >= 128) {
        int idx = 2 * base + (t - 128);
        const int lim = 2 * N - 1; if (idx > lim) idx = lim;
        xa[t - 128] = a[idx];
    }

    bf16x8 afrag[2][4];
    float b1v[2][4], w2v[2][4];
    const bf16x8* __restrict__ fb = (const bf16x8*)gfrag;
#pragma unroll
    for (int jt = 0; jt < 2; ++jt) {
        const int j16 = 2 * wq + jt;
#pragma unroll
        for (int s = 0; s < 4; ++s)
            afrag[jt][s] = fb[(j16 * 4 + s) * 64 + lane];
        const f32x4 bv = *(const f32x4*)&gbw[(j16 * 64 + lane) * 8];
        const f32x4 wv = *(const f32x4*)&gbw[(j16 * 64 + lane) * 8 + 4];
#pragma unroll
        for (int r = 0; r < 4; ++r) { b1v[jt][r] = bv[r]; w2v[jt][r] = wv[r]; }
    }
    __syncthreads();

    {   // layer 0
        const int j    = t & 127;
        const int half = t >> 7;
        const float w00 = g0_w[0 * HID + j];
        const float w01 = g0_w[1 * HID + j];
        const float w02 = g0_w[2 * HID + j];
        const float b0  = g0_b[j];
#pragma unroll 4
        for (int i = 0; i < 32; ++i) {
            const int nn = half * 32 + i;
            h0bf[nn * PITCH + j] = __float2bfloat16(
                fast_tanh(b0 + xv[nn] * w00 + xa[2 * nn] * w01 + xa[2 * nn + 1] * w02));
        }
    }
    __syncthreads();

#pragma unroll
    for (int nt = 0; nt < 4; ++nt) {
        const int n = nt * 16 + m;
        f32x4 acc0 = {0.f, 0.f, 0.f, 0.f};
        f32x4 acc1 = {0.f, 0.f, 0.f, 0.f};
#pragma unroll
        for (int s = 0; s < 4; ++s) {
            const bf16x8 b = *(const bf16x8*)&h0bf[n * PITCH + 32 * s + 8 * kg];
            acc0 = __builtin_amdgcn_mfma_f32_16x16x32_bf16(afrag[0][s], b, acc0, 0, 0, 0);
            acc1 = __builtin_amdgcn_mfma_f32_16x16x32_bf16(afrag[1][s], b, acc1, 0, 0, 0);
        }
        float p = 0.f;
#pragma unroll
        for (int r = 0; r < 4; ++r) {
            p += w2v[0][r] * fast_tanh(acc0[r] + b1v[0][r]);
            p += w2v[1][r] * fast_tanh(acc1[r] + b1v[1][r]);
        }
        p += __shfl_down(p, 32);
        p += __shfl_down(p, 16);
        if (lane < 16) red[wq][nt][lane] = p;
    }
    __syncthreads();

    if (t < NPB) {
        const int node = base + t;
        if (node < N) {
            const float g = red[0][t >> 4][t & 15] + red[1][t >> 4][t & 15]
                          + red[2][t >> 4][t & 15] + red[3][t >> 4][t & 15]
                          + g2_b[0];
            gsq[node] = g * g;
        }
    }
}

// ---------------------------------------------------------------------------
// edge scatter via LDS binning: 2 chunks x B parts; no global atomics.
// bf16 partial flush; c = blk>>7 pairs slice-sharing blocks on one XCD.
// ---------------------------------------------------------------------------
__global__ __launch_bounds__(1024) void edge_kernel(
    const int* __restrict__ src, const int* __restrict__ dst,
    const float* __restrict__ W, const float* __restrict__ gsq,
    __hip_bfloat16* __restrict__ partial, int B, int N, int Np, int E)
{
    __shared__ float loc[CH0];
    const int t = threadIdx.x;
    const int c = blockIdx.x >> 7;          // requires 2B == 256 blocks
    const int p = blockIdx.x & 127;

    int chN = c ? (N - CH0) : CH0;
    if (chN > CH0) chN = CH0; if (chN < 0) chN = 0;

    const f32x4 z4 = {0.f, 0.f, 0.f, 0.f};
    const int chZ = (chN + 3) & ~3;
    for (int i = 4 * t; i < chZ; i += 4096) *(f32x4*)&loc[i] = z4;
    __syncthreads();

    int cnt = (E + B - 1) / B;
    cnt = (cnt + 3) & ~3;
    const int start = p * cnt;
    int end = start + cnt; if (end > E) end = E;
    const int coff = c << 15;

    if (start < end) {
        const int nvec = (end - start) & ~3;
        for (int i = 4 * t; i < nvec; i += 4096) {
            const int e = start + i;
            const int4   s4 = *(const int4*)&src[e];
            const int4   d4 = *(const int4*)&dst[e];
            const float4 w4 = *(const float4*)&W[e];
            if ((d4.x >> 15) == c) atomicAdd(&loc[d4.x - coff], w4.x * gsq[s4.x]);
            if ((d4.y >> 15) == c) atomicAdd(&loc[d4.y - coff], w4.y * gsq[s4.y]);
            if ((d4.z >> 15) == c) atomicAdd(&loc[d4.z - coff], w4.z * gsq[s4.z]);
            if ((d4.w >> 15) == c) atomicAdd(&loc[d4.w - coff], w4.w * gsq[s4.w]);
        }
        for (int e = start + nvec + t; e < end; e += 1024) {
            const int d = dst[e];
            if ((d >> 15) == c) atomicAdd(&loc[d - coff], W[e] * gsq[src[e]]);
        }
    }
    __syncthreads();

    // flush as bf16
    __hip_bfloat16* __restrict__ dp = partial + (size_t)p * Np + coff;
    const int chV = chN & ~7;
    for (int i = 8 * t; i < chV; i += 8192) {
        const f32x4 lo = *(const f32x4*)&loc[i];
        const f32x4 hi = *(const f32x4*)&loc[i + 4];
        bf16x8 o;
#pragma unroll
        for (int r = 0; r < 4; ++r) { o[r] = f2bf(lo[r]); o[4 + r] = f2bf(hi[r]); }
        *(bf16x8*)&dp[i] = o;
    }
    for (int i = chV + t; i < chN; i += 1024) dp[i] = __float2bfloat16(loc[i]);
}

// ---------------------------------------------------------------------------
// node f_theta: out[n] = MLP3(v, a, msg, excitation); msg = sum of B partials
// ---------------------------------------------------------------------------
__global__ __launch_bounds__(256) void node_f_kernel(
    const float* __restrict__ v, const float* __restrict__ a,
    const float* __restrict__ exc, const __hip_bfloat16* __restrict__ partial,
    int B, int Np,
    const float* __restrict__ f0_w, const float* __restrict__ f0_b,
    const short* __restrict__ ffrag, const float* __restrict__ fbw,
    const float* __restrict__ f2_b,
    float* __restrict__ out, int N)
{
    const int t    = threadIdx.x;
    const int lane = t & 63;
    const int wq   = t >> 6;
    const int base = blockIdx.x * NPB;
    const int m    = lane & 15;
    const int kg   = lane >> 4;

    __shared__ __align__(16) __hip_bfloat16 h0bf[NPB * PITCH];
    __shared__ float xv[NPB];
    __shared__ float xe[NPB];
    __shared__ float xa[2 * NPB];
    __shared__ float xm4[4][NPB];
    __shared__ float red[4][4][16];

    if (t < NPB) {
        int node = base + t; if (node >= N) node = N - 1;
        xv[t] = v[node];
    } else if (t < 128) {
        int node = base + (t - 64); if (node >= N) node = N - 1;
        xe[t - 64] = exc[node];
    } else {
        int idx = 2 * base + (t - 128);
        const int lim = 2 * N - 1; if (idx > lim) idx = lim;
        xa[t - 128] = a[idx];
    }
    {
        const int n16 = t & 63, grp = t >> 6;
        int node = base + n16; if (node >= N) node = N - 1;
        const int pb = B >> 2;
        float s = 0.f;
        for (int p = grp * pb; p < (grp + 1) * pb; ++p)
            s += __bfloat162float(partial[(size_t)p * Np + node]);
        xm4[grp][n16] = s;
    }

    bf16x8 afrag[2][4];
    float b1v[2][4], w2v[2][4];
    const bf16x8* __restrict__ fb = (const bf16x8*)ffrag;
#pragma unroll
    for (int jt = 0; jt < 2; ++jt) {
        const int j16 = 2 * wq + jt;
#pragma unroll
        for (int s = 0; s < 4; ++s)
            afrag[jt][s] = fb[(j16 * 4 + s) * 64 + lane];
        const f32x4 bv = *(const f32x4*)&fbw[(j16 * 64 + lane) * 8];
        const f32x4 wv = *(const f32x4*)&fbw[(j16 * 64 + lane) * 8 + 4];
#pragma unroll
        for (int r = 0; r < 4; ++r) { b1v[jt][r] = bv[r]; w2v[jt][r] = wv[r]; }
    }
    __syncthreads();

    {   // layer 0 (5 inputs)
        const int j    = t & 127;
        const int half = t >> 7;
        const float w00 = f0_w[0 * HID + j];
        const float w01 = f0_w[1 * HID + j];
        const float w02 = f0_w[2 * HID + j];
        const float w03 = f0_w[3 * HID + j];
        const float w04 = f0_w[4 * HID + j];
        const float b0  = f0_b[j];
#pragma unroll 4
        for (int i = 0; i < 32; ++i) {
            const int nn = half * 32 + i;
            const float x3 = (xm4[0][nn] + xm4[1][nn]) + (xm4[2][nn] + xm4[3][nn]);
            h0bf[nn * PITCH + j] = __float2bfloat16(
                fast_tanh(b0 + xv[nn] * w00 + xa[2 * nn] * w01 + xa[2 * nn + 1] * w02
                             + x3 * w03 + xe[nn] * w04));
        }
    }
    __syncthreads();

#pragma unroll
    for (int nt = 0; nt < 4; ++nt) {
        const int n = nt * 16 + m;
        f32x4 acc0 = {0.f, 0.f, 0.f, 0.f};
        f32x4 acc1 = {0.f, 0.f, 0.f, 0.f};
#pragma unroll
        for (int s = 0; s < 4; ++s) {
            const bf16x8 b = *(const bf16x8*)&h0bf[n * PITCH + 32 * s + 8 * kg];
            acc0 = __builtin_amdgcn_mfma_f32_16x16x32_bf16(afrag[0][s], b, acc0, 0, 0, 0);
            acc1 = __builtin_amdgcn_mfma_f32_16x16x32_bf16(afrag[1][s], b, acc1, 0, 0, 0);
        }
        float p = 0.f;
#pragma unroll
        for (int r = 0; r < 4; ++r) {
            p += w2v[0][r] * fast_tanh(acc0[r] + b1v[0][r]);
            p += w2v[1][r] * fast_tanh(acc1[r] + b1v[1][r]);
        }
        p += __shfl_down(p, 32);
        p += __shfl_down(p, 16);
        if (lane < 16) red[wq][nt][lane] = p;
    }
    __syncthreads();

    if (t < NPB) {
        const int node = base + t;
        if (node < N) {
            out[node] = red[0][t >> 4][t & 15] + red[1][t >> 4][t & 15]
                      + red[2][t >> 4][t & 15] + red[3][t >> 4][t & 15]
                      + f2_b[0];
        }
    }
}

extern "C" void kernel_launch(void* const* d_in, const int* in_sizes, int n_in,
                              void* d_out, int out_size, void* d_ws, size_t ws_size,
                              hipStream_t stream)
{
    const float* v    = (const float*)d_in[0];
    const float* exc  = (const float*)d_in[1];
    const int*   esrc = (const int*)d_in[2];
    const int*   edst = (const int*)d_in[3];
    const float* a    = (const float*)d_in[4];
    const float* W    = (const float*)d_in[5];
    const float* g0_w = (const float*)d_in[6];
    const float* g0_b = (const float*)d_in[7];
    const float* g1_w = (const float*)d_in[8];
    const float* g1_b = (const float*)d_in[9];
    const float* g2_w = (const float*)d_in[10];
    const float* g2_b = (const float*)d_in[11];
    const float* f0_w = (const float*)d_in[12];
    const float* f0_b = (const float*)d_in[13];
    const float* f1_w = (const float*)d_in[14];
    const float* f1_b = (const float*)d_in[15];
    const float* f2_w = (const float*)d_in[16];
    const float* f2_b = (const float*)d_in[17];

    const int N = in_sizes[0];   // 50000
    const int E = in_sizes[2];   // 1600000

    const int B  = 128;                       // edge parts (grid = 2*B = 256)
    const int Np = (N + 7) & ~7;              // bf16 partial pitch

    float* gsq = (float*)d_ws;                               // N floats
    __hip_bfloat16* partial = (__hip_bfloat16*)(gsq + N);    // B*Np bf16
    short* gfrag = (short*)(partial + (size_t)B * Np);       // FRAGN shorts
    short* ffrag = gfrag + FRAGN;                            // FRAGN shorts
    float* gbw   = (float*)(ffrag + FRAGN);                  // 4096 floats
    float* fbw   = gbw + 4096;                               // 4096 floats

    const int nblocks = (N + NPB - 1) / NPB;   // 782

    prep_kernel<<<20, 256, 0, stream>>>(g1_w, g1_b, g2_w, f1_w, f1_b, f2_w,
                                        gfrag, ffrag, gbw, fbw);

    node_g_kernel<<<nblocks, 256, 0, stream>>>(v, a, g0_w, g0_b,
                                               gfrag, gbw, g2_b, gsq, N);

    edge_kernel<<<2 * B, 1024, 0, stream>>>(esrc, edst, W, gsq, partial,
                                            B, N, Np, E);

    node_f_kernel<<<nblocks, 256, 0, stream>>>(v, a, exc, partial, B, Np,
                                               f0_w, f0_b, ffrag, fbw, f2_b,
                                               (float*)d_out, N);
}